// Round 9
// baseline (523.606 us; speedup 1.0000x reference)
//
#include <hip/hip_runtime.h>
#include <math.h>

#define S 4096
#define QK_SCALE 0.17677669529663687f  // 1/sqrt(32)
#define LOG2E    1.44269504088896f
#define SPLIT 8
#define KS (S / SPLIT)                 // 512 keys per split

typedef _Float16 f16x8 __attribute__((ext_vector_type(8)));
typedef _Float16 f16x4 __attribute__((ext_vector_type(4)));
typedef _Float16 f16x2 __attribute__((ext_vector_type(2)));
typedef float f32x4 __attribute__((ext_vector_type(4)));

// ---------------------------------------------------------------------------
// MFMA lane map (HW-verified R4): A-frag m=l&15, k=(l>>4)*8+j; B-frag n=l&15;
// C reg r: row=(l>>4)*4+r, col=l&15. 128x128 block tile, 4 waves (64x64 each).
// ---------------------------------------------------------------------------
__device__ __forceinline__ void stageA_f16(_Float16 (*dst)[72], const _Float16* src,
                                           int ld, int row0, int col0, int tid) {
    int sr = tid >> 1, sc = (tid & 1) * 32;
    const _Float16* p = src + (size_t)(row0 + sr) * ld + col0 + sc;
#pragma unroll
    for (int v = 0; v < 4; v++)
        *(f16x8*)&dst[sr][sc + v * 8] = *(const f16x8*)(p + v * 8);
}

__device__ __forceinline__ void stageB_f32(_Float16 (*dst)[72], const float* src,
                                           int ld, int row0, int col0, int tid) {
    int sr = tid >> 1, sc = (tid & 1) * 32;
    const float* p = src + (size_t)(row0 + sr) * ld + col0 + sc;
#pragma unroll
    for (int v = 0; v < 4; v++) {
        float4 a = ((const float4*)p)[v * 2];
        float4 b = ((const float4*)p)[v * 2 + 1];
        f16x8 h = {(_Float16)a.x, (_Float16)a.y, (_Float16)a.z, (_Float16)a.w,
                   (_Float16)b.x, (_Float16)b.y, (_Float16)b.z, (_Float16)b.w};
        *(f16x8*)&dst[sr][sc + v * 8] = h;
    }
}

// stage a full 128x128 fp32 chunk -> fp16 LDS [128][136]
__device__ __forceinline__ void stage128w(_Float16 (*dst)[136], const float* src,
                                          int ld, int row0, int col0, int tid) {
    int sr = tid >> 1, sc = (tid & 1) * 64;
    const float* p = src + (size_t)(row0 + sr) * ld + col0 + sc;
#pragma unroll
    for (int v = 0; v < 8; v++) {
        float4 a = ((const float4*)p)[v * 2];
        float4 b = ((const float4*)p)[v * 2 + 1];
        f16x8 h = {(_Float16)a.x, (_Float16)a.y, (_Float16)a.z, (_Float16)a.w,
                   (_Float16)b.x, (_Float16)b.y, (_Float16)b.z, (_Float16)b.w};
        *(f16x8*)&dst[sr][sc + v * 8] = h;
    }
}

// stage a full 128x128 fp16 row-block -> LDS [128][136]
__device__ __forceinline__ void stage128h(_Float16 (*dst)[136], const _Float16* src,
                                          int row0, int tid) {
    int sr = tid >> 1, sc = (tid & 1) * 64;
    const _Float16* p = src + (size_t)(row0 + sr) * 128 + sc;
#pragma unroll
    for (int v = 0; v < 8; v++)
        *(f16x8*)&dst[sr][sc + v * 8] = *(const f16x8*)(p + v * 8);
}

__device__ __forceinline__ void mfma_tiles(_Float16 (*Ah)[72], _Float16 (*Bh)[72],
                                           int wrow, int wcol, int lc, int lr,
                                           f32x4 acc[4][4]) {
#pragma unroll
    for (int ks = 0; ks < 2; ks++) {
        f16x8 afr[4], bfr[4];
#pragma unroll
        for (int t = 0; t < 4; t++) {
            afr[t] = *(const f16x8*)&Ah[wrow + t * 16 + lc][ks * 32 + lr * 8];
            bfr[t] = *(const f16x8*)&Bh[wcol + t * 16 + lc][ks * 32 + lr * 8];
        }
#pragma unroll
        for (int i = 0; i < 4; i++)
#pragma unroll
            for (int j = 0; j < 4; j++)
                acc[i][j] = __builtin_amdgcn_mfma_f32_16x16x32_f16(
                    afr[i], bfr[j], acc[i][j], 0, 0, 0);
    }
}

template <int LDA, int LDB, int NK>
__device__ __forceinline__ void mfma_kloop(const _Float16 (*Ah)[LDA],
                                           const _Float16 (*Bh)[LDB],
                                           int wrow, int wcol, int lc, int lr,
                                           f32x4 acc[4][4]) {
#pragma unroll
    for (int ks = 0; ks < NK; ks++) {
        f16x8 afr[4], bfr[4];
#pragma unroll
        for (int t = 0; t < 4; t++) {
            afr[t] = *(const f16x8*)&Ah[wrow + t * 16 + lc][ks * 32 + lr * 8];
            bfr[t] = *(const f16x8*)&Bh[wcol + t * 16 + lc][ks * 32 + lr * 8];
        }
#pragma unroll
        for (int i = 0; i < 4; i++)
#pragma unroll
            for (int j = 0; j < 4; j++)
                acc[i][j] = __builtin_amdgcn_mfma_f32_16x16x32_f16(
                    afr[i], bfr[j], acc[i][j], 0, 0, 0);
    }
}

// ---------------------------------------------------------------------------
// copy: x(fp32), xh(fp16) <- src
// ---------------------------------------------------------------------------
__global__ __launch_bounds__(256) void copy_x(const float* __restrict__ a,
                                              float* __restrict__ x,
                                              _Float16* __restrict__ xh) {
    int i = blockIdx.x * 256 + threadIdx.x;
    float4 v = ((const float4*)a)[i];
    ((float4*)x)[i] = v;
    f16x4 h = {(_Float16)v.x, (_Float16)v.y, (_Float16)v.z, (_Float16)v.w};
    ((f16x4*)xh)[i] = h;
}

// ---------------------------------------------------------------------------
// QKV GEMM, fused output conversion. grid (32, 3): by=0 -> qh (scaled by
// QK_SCALE*log2e for exp2 softmax), by=1 -> kh, by=2 -> vt (transposed).
// ---------------------------------------------------------------------------
__global__ __launch_bounds__(256) void gemm_qkv(const _Float16* __restrict__ xh,
                                                const float* __restrict__ W,
                                                const float* __restrict__ bias,
                                                _Float16* __restrict__ qh,
                                                _Float16* __restrict__ kh,
                                                _Float16* __restrict__ vt)
{
    __shared__ _Float16 Ah[128][72], Bh[128][72];
    int tid = threadIdx.x, w = tid >> 6, l = tid & 63, lc = l & 15, lr = l >> 4;
    int wrow = (w >> 1) * 64, wcol = (w & 1) * 64;
    int m0 = blockIdx.x * 128, by = blockIdx.y;

    f32x4 acc[4][4];
#pragma unroll
    for (int i = 0; i < 4; i++)
#pragma unroll
        for (int j = 0; j < 4; j++) acc[i][j] = {0.f, 0.f, 0.f, 0.f};

#pragma unroll
    for (int k0 = 0; k0 < 128; k0 += 64) {
        __syncthreads();
        stageA_f16(Ah, xh, 128, m0, k0, tid);
        stageB_f32(Bh, W, 128, by * 128, k0, tid);
        __syncthreads();
        mfma_tiles(Ah, Bh, wrow, wcol, lc, lr, acc);
    }

#pragma unroll
    for (int i = 0; i < 4; i++) {
        int mb = m0 + wrow + i * 16 + lr * 4;
#pragma unroll
        for (int j = 0; j < 4; j++) {
            int n = wcol + j * 16 + lc;
            float bb = bias[by * 128 + n];
            if (by == 0) {
#pragma unroll
                for (int r = 0; r < 4; r++)
                    qh[(size_t)(mb + r) * 128 + n] =
                        (_Float16)((acc[i][j][r] + bb) * (QK_SCALE * LOG2E));
            } else if (by == 1) {
                int hh = n >> 5, d = n & 31;
#pragma unroll
                for (int r = 0; r < 4; r++)
                    kh[((size_t)hh * S + mb + r) * 32 + d] =
                        (_Float16)(acc[i][j][r] + bb);
            } else {
                f16x4 pk;
#pragma unroll
                for (int r = 0; r < 4; r++) pk[r] = (_Float16)(acc[i][j][r] + bb);
                *(f16x4*)&vt[(size_t)n * S + mb] = pk;
            }
        }
    }
}

// ---------------------------------------------------------------------------
// MFMA flash attention, split-K over keys (unchanged from R8): no online max
// (scores bounded), exp2, per-lane l accumulation, fp16 partials.
// ---------------------------------------------------------------------------
__global__ __launch_bounds__(256) void attn_mfma(const _Float16* __restrict__ qh,
                                                 const _Float16* __restrict__ kh,
                                                 const _Float16* __restrict__ vt,
                                                 _Float16* __restrict__ part,
                                                 float* __restrict__ mll)
{
    __shared__ _Float16 Ks[64][48];
    __shared__ _Float16 Vt[32][72];
    __shared__ _Float16 Ps[4][16][72];
    int h = blockIdx.y, q0 = blockIdx.x * 64, z = blockIdx.z;
    int tid = threadIdx.x;
    int w = tid >> 6, l = tid & 63;
    int lc = l & 15, lr = l >> 4;

    f16x8 qf = *(const f16x8*)&qh[(size_t)(q0 + w * 16 + lc) * 128 + h * 32 + lr * 8];

    f32x4 o0 = {0.f, 0.f, 0.f, 0.f}, o1 = {0.f, 0.f, 0.f, 0.f};
    float lp[4] = {0.f, 0.f, 0.f, 0.f};

    const _Float16* khh = kh + (size_t)h * S * 32;
    const _Float16* vth = vt + (size_t)h * 32 * S;

    for (int k0 = z * KS; k0 < z * KS + KS; k0 += 64) {
        __syncthreads();
        {
            int row = tid >> 2, dg = (tid & 3) * 8;
            *(f16x8*)&Ks[row][dg] = *(const f16x8*)&khh[(size_t)(k0 + row) * 32 + dg];
            int dim = tid >> 3, kg = (tid & 7) * 8;
            *(f16x8*)&Vt[dim][kg] = *(const f16x8*)&vth[(size_t)dim * S + k0 + kg];
        }
        __syncthreads();

        f32x4 st[4];
#pragma unroll
        for (int t = 0; t < 4; t++) {
            f16x8 kf = *(const f16x8*)&Ks[t * 16 + lc][lr * 8];
            f32x4 zz = {0.f, 0.f, 0.f, 0.f};
            st[t] = __builtin_amdgcn_mfma_f32_16x16x32_f16(qf, kf, zz, 0, 0, 0);
        }

#pragma unroll
        for (int i = 0; i < 4; i++) {
            float p0 = exp2f(st[0][i]), p1 = exp2f(st[1][i]);
            float p2 = exp2f(st[2][i]), p3 = exp2f(st[3][i]);
            lp[i] += (p0 + p1) + (p2 + p3);
            Ps[w][lr * 4 + i][lc]      = (_Float16)p0;
            Ps[w][lr * 4 + i][16 + lc] = (_Float16)p1;
            Ps[w][lr * 4 + i][32 + lc] = (_Float16)p2;
            Ps[w][lr * 4 + i][48 + lc] = (_Float16)p3;
        }
        asm volatile("s_waitcnt lgkmcnt(0)" ::: "memory");
#pragma unroll
        for (int ch = 0; ch < 2; ch++) {
            f16x8 pf = *(const f16x8*)&Ps[w][lc][ch * 32 + lr * 8];
            f16x8 v0 = *(const f16x8*)&Vt[lc][ch * 32 + lr * 8];
            f16x8 v1 = *(const f16x8*)&Vt[16 + lc][ch * 32 + lr * 8];
            o0 = __builtin_amdgcn_mfma_f32_16x16x32_f16(pf, v0, o0, 0, 0, 0);
            o1 = __builtin_amdgcn_mfma_f32_16x16x32_f16(pf, v1, o1, 0, 0, 0);
        }
    }

#pragma unroll
    for (int i = 0; i < 4; i++) {
#pragma unroll
        for (int off = 1; off < 16; off <<= 1) lp[i] += __shfl_xor(lp[i], off);
    }

    _Float16* pz = part + (size_t)z * 524288;
#pragma unroll
    for (int i = 0; i < 4; i++) {
        int q = q0 + w * 16 + lr * 4 + i;
        pz[(size_t)q * 128 + h * 32 + lc]      = (_Float16)o0[i];
        pz[(size_t)q * 128 + h * 32 + 16 + lc] = (_Float16)o1[i];
        if (lc == 0) mll[((size_t)z * 4 + h) * 4096 + q] = lp[i];
    }
}

// ---------------------------------------------------------------------------
// Wo GEMM with the split-attention MERGE fused into A-staging, + residual +
// LayerNorm epilogue. grid (32). A[q][c] = (sum_s part_s[q][c]) / sum_s l_s.
// Each staged 32-col group lies in one head (c>>5).
// ---------------------------------------------------------------------------
__global__ __launch_bounds__(256) void wo_ln_merge(const _Float16* __restrict__ part,
                                                   const float* __restrict__ mll,
                                                   const float* __restrict__ W,
                                                   const float* __restrict__ bias,
                                                   float* __restrict__ x,
                                                   _Float16* __restrict__ xh,
                                                   const float* __restrict__ g,
                                                   const float* __restrict__ b)
{
    __shared__ _Float16 Ah[128][72], Bh[128][72];
    __shared__ float Red[128][2][2];
    int tid = threadIdx.x, w = tid >> 6, l = tid & 63, lc = l & 15, lr = l >> 4;
    int wrow = (w >> 1) * 64, wcol = (w & 1) * 64;
    int m0 = blockIdx.x * 128;

    f32x4 acc[4][4];
#pragma unroll
    for (int i = 0; i < 4; i++)
#pragma unroll
        for (int j = 0; j < 4; j++) acc[i][j] = {0.f, 0.f, 0.f, 0.f};

#pragma unroll
    for (int k0 = 0; k0 < 128; k0 += 64) {
        __syncthreads();
        {   // merge-staging of A
            int sr = tid >> 1, sc = (tid & 1) * 32;
            int q = m0 + sr;
            int hh = (k0 + sc) >> 5;
            float lsum = 0.f;
#pragma unroll
            for (int s = 0; s < SPLIT; s++)
                lsum += mll[((size_t)s * 4 + hh) * 4096 + q];
            float am[32];
#pragma unroll
            for (int e = 0; e < 32; e++) am[e] = 0.f;
#pragma unroll
            for (int s = 0; s < SPLIT; s++) {
                const _Float16* p = part + (size_t)s * 524288 + (size_t)q * 128 + k0 + sc;
#pragma unroll
                for (int v = 0; v < 4; v++) {
                    f16x8 t = *(const f16x8*)(p + v * 8);
#pragma unroll
                    for (int e = 0; e < 8; e++) am[v * 8 + e] += (float)t[e];
                }
            }
            float inv = 1.f / lsum;
#pragma unroll
            for (int v = 0; v < 4; v++) {
                f16x8 hv;
#pragma unroll
                for (int e = 0; e < 8; e++) hv[e] = (_Float16)(am[v * 8 + e] * inv);
                *(f16x8*)&Ah[sr][sc + v * 8] = hv;
            }
        }
        stageB_f32(Bh, W, 128, 0, k0, tid);
        __syncthreads();
        mfma_tiles(Ah, Bh, wrow, wcol, lc, lr, acc);
    }

    // residual + bias
#pragma unroll
    for (int i = 0; i < 4; i++) {
        int mb = m0 + wrow + i * 16 + lr * 4;
#pragma unroll
        for (int j = 0; j < 4; j++) {
            int n = wcol + j * 16 + lc;
            float bb = bias[n];
#pragma unroll
            for (int r = 0; r < 4; r++)
                acc[i][j][r] += bb + x[(size_t)(mb + r) * 128 + n];
        }
    }
    // LayerNorm across the 128 cols (2 waves per row-half)
#pragma unroll
    for (int i = 0; i < 4; i++)
#pragma unroll
        for (int r = 0; r < 4; r++) {
            float s1 = 0.f, s2 = 0.f;
#pragma unroll
            for (int j = 0; j < 4; j++) {
                float t = acc[i][j][r];
                s1 += t; s2 += t * t;
            }
#pragma unroll
            for (int off = 1; off < 16; off <<= 1) {
                s1 += __shfl_xor(s1, off);
                s2 += __shfl_xor(s2, off);
            }
            if (lc == 0) {
                int rl = wrow + i * 16 + lr * 4 + r;
                Red[rl][w & 1][0] = s1;
                Red[rl][w & 1][1] = s2;
            }
        }
    __syncthreads();
#pragma unroll
    for (int i = 0; i < 4; i++)
#pragma unroll
        for (int r = 0; r < 4; r++) {
            int rl = wrow + i * 16 + lr * 4 + r;
            float S1 = Red[rl][0][0] + Red[rl][1][0];
            float S2 = Red[rl][0][1] + Red[rl][1][1];
            float mean = S1 * (1.0f / 128.0f);
            float var = S2 * (1.0f / 128.0f) - mean * mean;
            float inv = rsqrtf(var + 1e-5f);
            int m = m0 + rl;
#pragma unroll
            for (int j = 0; j < 4; j++) {
                int n = wcol + j * 16 + lc;
                float o = (acc[i][j][r] - mean) * inv * g[n] + b[n];
                x[(size_t)m * 128 + n] = o;
                xh[(size_t)m * 128 + n] = (_Float16)o;
            }
        }
}

// ---------------------------------------------------------------------------
// Fully fused FFN: relu(x@W1^T+b1)@W2^T + b2 + residual -> LayerNorm -> x,xh.
// grid (32). W1/W2 processed in 8 chunks of 128; fh chunk lives in LDS only.
// LDS ~110 KB -> 1 block/CU (fine, grid is 32).
// ---------------------------------------------------------------------------
__global__ __launch_bounds__(256) void ffn_fused(const _Float16* __restrict__ xhin,
                                                 const float* __restrict__ W1,
                                                 const float* __restrict__ b1,
                                                 const float* __restrict__ W2,
                                                 const float* __restrict__ b2,
                                                 float* __restrict__ x,
                                                 _Float16* __restrict__ xh,
                                                 const float* __restrict__ g,
                                                 const float* __restrict__ b)
{
    __shared__ _Float16 Xh[128][136];   // x block, A-layout, full K=128
    __shared__ _Float16 Wb[128][136];   // weight chunk (reused W1c/W2c)
    __shared__ _Float16 Fh[128][140];   // fh chunk, A-layout (pad 140: writes 2-way)
    __shared__ float Red[128][2][2];
    int tid = threadIdx.x, w = tid >> 6, l = tid & 63, lc = l & 15, lr = l >> 4;
    int wrow = (w >> 1) * 64, wcol = (w & 1) * 64;
    int m0 = blockIdx.x * 128;

    stage128h(Xh, xhin, m0, tid);

    f32x4 oacc[4][4];
#pragma unroll
    for (int i = 0; i < 4; i++)
#pragma unroll
        for (int j = 0; j < 4; j++) oacc[i][j] = {0.f, 0.f, 0.f, 0.f};

    for (int c = 0; c < 8; c++) {
        __syncthreads();                 // Xh ready (c=0) / prev mfma2 done
        stage128w(Wb, W1, 128, c * 128, 0, tid);
        __syncthreads();
        f32x4 facc[4][4];
#pragma unroll
        for (int i = 0; i < 4; i++)
#pragma unroll
            for (int j = 0; j < 4; j++) facc[i][j] = {0.f, 0.f, 0.f, 0.f};
        mfma_kloop<136, 136, 4>(Xh, Wb, wrow, wcol, lc, lr, facc);
        // relu + bias -> Fh (C-layout scatter into A-layout LDS)
#pragma unroll
        for (int i = 0; i < 4; i++)
#pragma unroll
            for (int j = 0; j < 4; j++) {
                int n = wcol + j * 16 + lc;
                float bb = b1[c * 128 + n];
#pragma unroll
                for (int r = 0; r < 4; r++)
                    Fh[wrow + i * 16 + lr * 4 + r][n] =
                        (_Float16)fmaxf(facc[i][j][r] + bb, 0.f);
            }
        __syncthreads();                 // Fh ready; Wb reads done
        stage128w(Wb, W2, 1024, 0, c * 128, tid);
        __syncthreads();
        mfma_kloop<140, 136, 4>(Fh, Wb, wrow, wcol, lc, lr, oacc);
    }

    // bias + residual
#pragma unroll
    for (int i = 0; i < 4; i++) {
        int mb = m0 + wrow + i * 16 + lr * 4;
#pragma unroll
        for (int j = 0; j < 4; j++) {
            int n = wcol + j * 16 + lc;
            float bb = b2[n];
#pragma unroll
            for (int r = 0; r < 4; r++)
                oacc[i][j][r] += bb + x[(size_t)(mb + r) * 128 + n];
        }
    }
    // LayerNorm
#pragma unroll
    for (int i = 0; i < 4; i++)
#pragma unroll
        for (int r = 0; r < 4; r++) {
            float s1 = 0.f, s2 = 0.f;
#pragma unroll
            for (int j = 0; j < 4; j++) {
                float t = oacc[i][j][r];
                s1 += t; s2 += t * t;
            }
#pragma unroll
            for (int off = 1; off < 16; off <<= 1) {
                s1 += __shfl_xor(s1, off);
                s2 += __shfl_xor(s2, off);
            }
            if (lc == 0) {
                int rl = wrow + i * 16 + lr * 4 + r;
                Red[rl][w & 1][0] = s1;
                Red[rl][w & 1][1] = s2;
            }
        }
    __syncthreads();
#pragma unroll
    for (int i = 0; i < 4; i++)
#pragma unroll
        for (int r = 0; r < 4; r++) {
            int rl = wrow + i * 16 + lr * 4 + r;
            float S1 = Red[rl][0][0] + Red[rl][1][0];
            float S2 = Red[rl][0][1] + Red[rl][1][1];
            float mean = S1 * (1.0f / 128.0f);
            float var = S2 * (1.0f / 128.0f) - mean * mean;
            float inv = rsqrtf(var + 1e-5f);
            int m = m0 + rl;
#pragma unroll
            for (int j = 0; j < 4; j++) {
                int n = wcol + j * 16 + lc;
                float o = (oacc[i][j][r] - mean) * inv * g[n] + b[n];
                x[(size_t)m * 128 + n] = o;
                xh[(size_t)m * 128 + n] = (_Float16)o;
            }
        }
}

// ---------------------------------------------------------------------------
// fc1 + relu + fc2 + rownorm fused. grid (32). Writes aoh fp16.
// ---------------------------------------------------------------------------
__global__ __launch_bounds__(256) void fc_fused(const _Float16* __restrict__ xh,
                                                const float* __restrict__ W1f,
                                                const float* __restrict__ b1f,
                                                const float* __restrict__ W2f,
                                                const float* __restrict__ b2f,
                                                _Float16* __restrict__ aoh)
{
    __shared__ _Float16 Ah[128][72], Bh[128][72];
    __shared__ _Float16 X2[128][136];
    __shared__ float Red[128][2];
    int tid = threadIdx.x, w = tid >> 6, l = tid & 63, lc = l & 15, lr = l >> 4;
    int wrow = (w >> 1) * 64, wcol = (w & 1) * 64;
    int m0 = blockIdx.x * 128;

    f32x4 acc[4][4];
#pragma unroll
    for (int i = 0; i < 4; i++)
#pragma unroll
        for (int j = 0; j < 4; j++) acc[i][j] = {0.f, 0.f, 0.f, 0.f};

#pragma unroll
    for (int k0 = 0; k0 < 128; k0 += 64) {
        __syncthreads();
        stageA_f16(Ah, xh, 128, m0, k0, tid);
        stageB_f32(Bh, W1f, 128, 0, k0, tid);
        __syncthreads();
        mfma_tiles(Ah, Bh, wrow, wcol, lc, lr, acc);
    }
#pragma unroll
    for (int i = 0; i < 4; i++)
#pragma unroll
        for (int j = 0; j < 4; j++) {
            int n = wcol + j * 16 + lc;
            float bb = b1f[n];
#pragma unroll
            for (int r = 0; r < 4; r++)
                X2[wrow + i * 16 + lr * 4 + r][n] =
                    (_Float16)fmaxf(acc[i][j][r] + bb, 0.f);
        }
#pragma unroll
    for (int i = 0; i < 4; i++)
#pragma unroll
        for (int j = 0; j < 4; j++) acc[i][j] = {0.f, 0.f, 0.f, 0.f};

#pragma unroll
    for (int k0 = 0; k0 < 128; k0 += 64) {
        __syncthreads();
        stageB_f32(Bh, W2f, 128, 0, k0, tid);
        __syncthreads();
#pragma unroll
        for (int ks = 0; ks < 2; ks++) {
            f16x8 afr[4], bfr[4];
#pragma unroll
            for (int t = 0; t < 4; t++) {
                afr[t] = *(const f16x8*)&X2[wrow + t * 16 + lc][k0 + ks * 32 + lr * 8];
                bfr[t] = *(const f16x8*)&Bh[wcol + t * 16 + lc][ks * 32 + lr * 8];
            }
#pragma unroll
            for (int i = 0; i < 4; i++)
#pragma unroll
                for (int j = 0; j < 4; j++)
                    acc[i][j] = __builtin_amdgcn_mfma_f32_16x16x32_f16(
                        afr[i], bfr[j], acc[i][j], 0, 0, 0);
        }
    }

#pragma unroll
    for (int i = 0; i < 4; i++)
#pragma unroll
        for (int j = 0; j < 4; j++) {
            float bb = b2f[wcol + j * 16 + lc];
#pragma unroll
            for (int r = 0; r < 4; r++) acc[i][j][r] += bb;
        }
#pragma unroll
    for (int i = 0; i < 4; i++)
#pragma unroll
        for (int r = 0; r < 4; r++) {
            float s2 = 0.f;
#pragma unroll
            for (int j = 0; j < 4; j++) s2 += acc[i][j][r] * acc[i][j][r];
#pragma unroll
            for (int off = 1; off < 16; off <<= 1) s2 += __shfl_xor(s2, off);
            if (lc == 0) Red[wrow + i * 16 + lr * 4 + r][w & 1] = s2;
        }
    __syncthreads();
#pragma unroll
    for (int i = 0; i < 4; i++)
#pragma unroll
        for (int r = 0; r < 4; r++) {
            int rl = wrow + i * 16 + lr * 4 + r;
            float inv = rsqrtf(Red[rl][0] + Red[rl][1]);
            int m = m0 + rl;
#pragma unroll
            for (int j = 0; j < 4; j++) {
                int n = wcol + j * 16 + lc;
                aoh[(size_t)m * 128 + n] = (_Float16)(acc[i][j][r] * inv);
            }
        }
}

// ---------------------------------------------------------------------------
// Gram: C = max(aoh @ aoh^T, 1e-6), fp32 out. grid (32, 32).
// ---------------------------------------------------------------------------
__global__ __launch_bounds__(256) void gram_f16(const _Float16* __restrict__ aoh,
                                                float* __restrict__ C)
{
    __shared__ _Float16 Ah[128][72], Bh[128][72];
    int tid = threadIdx.x, w = tid >> 6, l = tid & 63, lc = l & 15, lr = l >> 4;
    int wrow = (w >> 1) * 64, wcol = (w & 1) * 64;
    int m0 = blockIdx.x * 128, n0 = blockIdx.y * 128;

    f32x4 acc[4][4];
#pragma unroll
    for (int i = 0; i < 4; i++)
#pragma unroll
        for (int j = 0; j < 4; j++) acc[i][j] = {0.f, 0.f, 0.f, 0.f};

#pragma unroll
    for (int k0 = 0; k0 < 128; k0 += 64) {
        __syncthreads();
        stageA_f16(Ah, aoh, 128, m0, k0, tid);
        stageA_f16(Bh, aoh, 128, n0, k0, tid);
        __syncthreads();
        mfma_tiles(Ah, Bh, wrow, wcol, lc, lr, acc);
    }

#pragma unroll
    for (int i = 0; i < 4; i++) {
        int mb = m0 + wrow + i * 16 + lr * 4;
#pragma unroll
        for (int j = 0; j < 4; j++) {
            int n = n0 + wcol + j * 16 + lc;
#pragma unroll
            for (int r = 0; r < 4; r++)
                C[(size_t)(mb + r) * 4096 + n] = fmaxf(acc[i][j][r], 1e-6f);
        }
    }
}

// ---------------------------------------------------------------------------
extern "C" void kernel_launch(void* const* d_in, const int* in_sizes, int n_in,
                              void* d_out, int out_size, void* d_ws, size_t ws_size,
                              hipStream_t stream)
{
    const float* src  = (const float*)d_in[0];
    const float* Wqkv = (const float*)d_in[1];
    const float* bqkv = (const float*)d_in[2];
    const float* Wo   = (const float*)d_in[3];
    const float* bo   = (const float*)d_in[4];
    const float* ln1g = (const float*)d_in[5];
    const float* ln1b = (const float*)d_in[6];
    const float* W1   = (const float*)d_in[7];
    const float* b1   = (const float*)d_in[8];
    const float* W2   = (const float*)d_in[9];
    const float* b2   = (const float*)d_in[10];
    const float* ln2g = (const float*)d_in[11];
    const float* ln2b = (const float*)d_in[12];
    const float* fc1W = (const float*)d_in[13];
    const float* fc1b = (const float*)d_in[14];
    const float* fc2W = (const float*)d_in[15];
    const float* fc2b = (const float*)d_in[16];

    float* ws = (float*)d_ws;
    float*    x   = ws;                                   // 524288 f32
    _Float16* xh  = (_Float16*)(ws + 524288);             // 524288 f16
    _Float16* aoh = (_Float16*)(ws + 786432);             // 524288 f16
    _Float16* qh  = (_Float16*)(ws + 1048576);            // 524288 f16
    _Float16* kh  = (_Float16*)(ws + 1310720);            // 524288 f16
    _Float16* vt  = (_Float16*)(ws + 1572864);            // 524288 f16
    float*    mll = ws + 1835008;                         // 131072 f32

    // d_out scratch (dead before gram writes):
    _Float16* apart = (_Float16*)((float*)d_out + 6291456);  // 8*524288 f16
    float*    out   = (float*)d_out;

    copy_x<<<512, 256, 0, stream>>>(src, x, xh);
    for (int l = 0; l < 3; l++) {
        gemm_qkv<<<dim3(32, 3), 256, 0, stream>>>(xh, Wqkv + l * 49152,
                                                  bqkv + l * 384, qh, kh, vt);
        attn_mfma<<<dim3(64, 4, SPLIT), 256, 0, stream>>>(qh, kh, vt, apart, mll);
        wo_ln_merge<<<32, 256, 0, stream>>>(apart, mll, Wo + l * 16384, bo + l * 128,
                                            x, xh, ln1g + l * 128, ln1b + l * 128);
        ffn_fused<<<32, 256, 0, stream>>>(xh, W1 + l * 131072, b1 + l * 1024,
                                          W2 + l * 131072, b2 + l * 128,
                                          x, xh, ln2g + l * 128, ln2b + l * 128);
    }
    fc_fused<<<32, 256, 0, stream>>>(xh, fc1W, fc1b, fc2W, fc2b, aoh);
    gram_f16<<<dim3(32, 32), 256, 0, stream>>>(aoh, out);
}

// Round 10
// 357.336 us; speedup vs baseline: 1.4653x; 1.4653x over previous
//
#include <hip/hip_runtime.h>
#include <math.h>

#define S 4096
#define QK_SCALE 0.17677669529663687f  // 1/sqrt(32)
#define LOG2E    1.44269504088896f
#define SPLIT 8
#define KS (S / SPLIT)                 // 512 keys per split

typedef _Float16 f16x8 __attribute__((ext_vector_type(8)));
typedef _Float16 f16x4 __attribute__((ext_vector_type(4)));
typedef _Float16 f16x2 __attribute__((ext_vector_type(2)));
typedef float f32x4 __attribute__((ext_vector_type(4)));

// ---------------------------------------------------------------------------
// MFMA lane map (HW-verified R4): A-frag m=l&15, k=(l>>4)*8+j; B-frag n=l&15;
// C reg r: row=(l>>4)*4+r, col=l&15. 128x128 block tile, 4 waves (64x64 each).
// NOTE (R9 lesson): never fuse so hard that the grid drops to 32 blocks while
// each block streams O(MB) of weights — per-CU load BW (~10-20 B/cyc) becomes
// the wall. Weight-streaming kernels need >=256 blocks.
// ---------------------------------------------------------------------------
__device__ __forceinline__ void stageA_f16(_Float16 (*dst)[72], const _Float16* src,
                                           int ld, int row0, int col0, int tid) {
    int sr = tid >> 1, sc = (tid & 1) * 32;
    const _Float16* p = src + (size_t)(row0 + sr) * ld + col0 + sc;
#pragma unroll
    for (int v = 0; v < 4; v++)
        *(f16x8*)&dst[sr][sc + v * 8] = *(const f16x8*)(p + v * 8);
}

__device__ __forceinline__ void stageB_f32(_Float16 (*dst)[72], const float* src,
                                           int ld, int row0, int col0, int tid) {
    int sr = tid >> 1, sc = (tid & 1) * 32;
    const float* p = src + (size_t)(row0 + sr) * ld + col0 + sc;
#pragma unroll
    for (int v = 0; v < 4; v++) {
        float4 a = ((const float4*)p)[v * 2];
        float4 b = ((const float4*)p)[v * 2 + 1];
        f16x8 h = {(_Float16)a.x, (_Float16)a.y, (_Float16)a.z, (_Float16)a.w,
                   (_Float16)b.x, (_Float16)b.y, (_Float16)b.z, (_Float16)b.w};
        *(f16x8*)&dst[sr][sc + v * 8] = h;
    }
}

__device__ __forceinline__ void mfma_tiles(_Float16 (*Ah)[72], _Float16 (*Bh)[72],
                                           int wrow, int wcol, int lc, int lr,
                                           f32x4 acc[4][4]) {
#pragma unroll
    for (int ks = 0; ks < 2; ks++) {
        f16x8 afr[4], bfr[4];
#pragma unroll
        for (int t = 0; t < 4; t++) {
            afr[t] = *(const f16x8*)&Ah[wrow + t * 16 + lc][ks * 32 + lr * 8];
            bfr[t] = *(const f16x8*)&Bh[wcol + t * 16 + lc][ks * 32 + lr * 8];
        }
#pragma unroll
        for (int i = 0; i < 4; i++)
#pragma unroll
            for (int j = 0; j < 4; j++)
                acc[i][j] = __builtin_amdgcn_mfma_f32_16x16x32_f16(
                    afr[i], bfr[j], acc[i][j], 0, 0, 0);
    }
}

// ---------------------------------------------------------------------------
// copy: x(fp32), xh(fp16) <- src
// ---------------------------------------------------------------------------
__global__ __launch_bounds__(256) void copy_x(const float* __restrict__ a,
                                              float* __restrict__ x,
                                              _Float16* __restrict__ xh) {
    int i = blockIdx.x * 256 + threadIdx.x;
    float4 v = ((const float4*)a)[i];
    ((float4*)x)[i] = v;
    f16x4 h = {(_Float16)v.x, (_Float16)v.y, (_Float16)v.z, (_Float16)v.w};
    ((f16x4*)xh)[i] = h;
}

// ---------------------------------------------------------------------------
// QKV GEMM, fused output conversion. grid (32, 3): by=0 -> qh (scaled by
// QK_SCALE*log2e for exp2 softmax), by=1 -> kh, by=2 -> vt (transposed).
// ---------------------------------------------------------------------------
__global__ __launch_bounds__(256) void gemm_qkv(const _Float16* __restrict__ xh,
                                                const float* __restrict__ W,
                                                const float* __restrict__ bias,
                                                _Float16* __restrict__ qh,
                                                _Float16* __restrict__ kh,
                                                _Float16* __restrict__ vt)
{
    __shared__ _Float16 Ah[128][72], Bh[128][72];
    int tid = threadIdx.x, w = tid >> 6, l = tid & 63, lc = l & 15, lr = l >> 4;
    int wrow = (w >> 1) * 64, wcol = (w & 1) * 64;
    int m0 = blockIdx.x * 128, by = blockIdx.y;

    f32x4 acc[4][4];
#pragma unroll
    for (int i = 0; i < 4; i++)
#pragma unroll
        for (int j = 0; j < 4; j++) acc[i][j] = {0.f, 0.f, 0.f, 0.f};

#pragma unroll
    for (int k0 = 0; k0 < 128; k0 += 64) {
        __syncthreads();
        stageA_f16(Ah, xh, 128, m0, k0, tid);
        stageB_f32(Bh, W, 128, by * 128, k0, tid);
        __syncthreads();
        mfma_tiles(Ah, Bh, wrow, wcol, lc, lr, acc);
    }

#pragma unroll
    for (int i = 0; i < 4; i++) {
        int mb = m0 + wrow + i * 16 + lr * 4;
#pragma unroll
        for (int j = 0; j < 4; j++) {
            int n = wcol + j * 16 + lc;
            float bb = bias[by * 128 + n];
            if (by == 0) {
#pragma unroll
                for (int r = 0; r < 4; r++)
                    qh[(size_t)(mb + r) * 128 + n] =
                        (_Float16)((acc[i][j][r] + bb) * (QK_SCALE * LOG2E));
            } else if (by == 1) {
                int hh = n >> 5, d = n & 31;
#pragma unroll
                for (int r = 0; r < 4; r++)
                    kh[((size_t)hh * S + mb + r) * 32 + d] =
                        (_Float16)(acc[i][j][r] + bb);
            } else {
                f16x4 pk;
#pragma unroll
                for (int r = 0; r < 4; r++) pk[r] = (_Float16)(acc[i][j][r] + bb);
                *(f16x4*)&vt[(size_t)n * S + mb] = pk;
            }
        }
    }
}

// ---------------------------------------------------------------------------
// MFMA flash attention, split-K over keys: no online max (scores bounded),
// exp2, per-lane l accumulation, fp16 partials.
// ---------------------------------------------------------------------------
__global__ __launch_bounds__(256) void attn_mfma(const _Float16* __restrict__ qh,
                                                 const _Float16* __restrict__ kh,
                                                 const _Float16* __restrict__ vt,
                                                 _Float16* __restrict__ part,
                                                 float* __restrict__ mll)
{
    __shared__ _Float16 Ks[64][48];
    __shared__ _Float16 Vt[32][72];
    __shared__ _Float16 Ps[4][16][72];
    int h = blockIdx.y, q0 = blockIdx.x * 64, z = blockIdx.z;
    int tid = threadIdx.x;
    int w = tid >> 6, l = tid & 63;
    int lc = l & 15, lr = l >> 4;

    f16x8 qf = *(const f16x8*)&qh[(size_t)(q0 + w * 16 + lc) * 128 + h * 32 + lr * 8];

    f32x4 o0 = {0.f, 0.f, 0.f, 0.f}, o1 = {0.f, 0.f, 0.f, 0.f};
    float lp[4] = {0.f, 0.f, 0.f, 0.f};

    const _Float16* khh = kh + (size_t)h * S * 32;
    const _Float16* vth = vt + (size_t)h * 32 * S;

    for (int k0 = z * KS; k0 < z * KS + KS; k0 += 64) {
        __syncthreads();
        {
            int row = tid >> 2, dg = (tid & 3) * 8;
            *(f16x8*)&Ks[row][dg] = *(const f16x8*)&khh[(size_t)(k0 + row) * 32 + dg];
            int dim = tid >> 3, kg = (tid & 7) * 8;
            *(f16x8*)&Vt[dim][kg] = *(const f16x8*)&vth[(size_t)dim * S + k0 + kg];
        }
        __syncthreads();

        f32x4 st[4];
#pragma unroll
        for (int t = 0; t < 4; t++) {
            f16x8 kf = *(const f16x8*)&Ks[t * 16 + lc][lr * 8];
            f32x4 zz = {0.f, 0.f, 0.f, 0.f};
            st[t] = __builtin_amdgcn_mfma_f32_16x16x32_f16(qf, kf, zz, 0, 0, 0);
        }

#pragma unroll
        for (int i = 0; i < 4; i++) {
            float p0 = exp2f(st[0][i]), p1 = exp2f(st[1][i]);
            float p2 = exp2f(st[2][i]), p3 = exp2f(st[3][i]);
            lp[i] += (p0 + p1) + (p2 + p3);
            Ps[w][lr * 4 + i][lc]      = (_Float16)p0;
            Ps[w][lr * 4 + i][16 + lc] = (_Float16)p1;
            Ps[w][lr * 4 + i][32 + lc] = (_Float16)p2;
            Ps[w][lr * 4 + i][48 + lc] = (_Float16)p3;
        }
        asm volatile("s_waitcnt lgkmcnt(0)" ::: "memory");
#pragma unroll
        for (int ch = 0; ch < 2; ch++) {
            f16x8 pf = *(const f16x8*)&Ps[w][lc][ch * 32 + lr * 8];
            f16x8 v0 = *(const f16x8*)&Vt[lc][ch * 32 + lr * 8];
            f16x8 v1 = *(const f16x8*)&Vt[16 + lc][ch * 32 + lr * 8];
            o0 = __builtin_amdgcn_mfma_f32_16x16x32_f16(pf, v0, o0, 0, 0, 0);
            o1 = __builtin_amdgcn_mfma_f32_16x16x32_f16(pf, v1, o1, 0, 0, 0);
        }
    }

#pragma unroll
    for (int i = 0; i < 4; i++) {
#pragma unroll
        for (int off = 1; off < 16; off <<= 1) lp[i] += __shfl_xor(lp[i], off);
    }

    _Float16* pz = part + (size_t)z * 524288;
#pragma unroll
    for (int i = 0; i < 4; i++) {
        int q = q0 + w * 16 + lr * 4 + i;
        pz[(size_t)q * 128 + h * 32 + lc]      = (_Float16)o0[i];
        pz[(size_t)q * 128 + h * 32 + 16 + lc] = (_Float16)o1[i];
        if (lc == 0) mll[((size_t)z * 4 + h) * 4096 + q] = lp[i];
    }
}

// ---------------------------------------------------------------------------
// Wo GEMM with the split-attention MERGE fused into A-staging, + residual +
// LayerNorm epilogue. grid (32).
// ---------------------------------------------------------------------------
__global__ __launch_bounds__(256) void wo_ln_merge(const _Float16* __restrict__ part,
                                                   const float* __restrict__ mll,
                                                   const float* __restrict__ W,
                                                   const float* __restrict__ bias,
                                                   float* __restrict__ x,
                                                   _Float16* __restrict__ xh,
                                                   const float* __restrict__ g,
                                                   const float* __restrict__ b)
{
    __shared__ _Float16 Ah[128][72], Bh[128][72];
    __shared__ float Red[128][2][2];
    int tid = threadIdx.x, w = tid >> 6, l = tid & 63, lc = l & 15, lr = l >> 4;
    int wrow = (w >> 1) * 64, wcol = (w & 1) * 64;
    int m0 = blockIdx.x * 128;

    f32x4 acc[4][4];
#pragma unroll
    for (int i = 0; i < 4; i++)
#pragma unroll
        for (int j = 0; j < 4; j++) acc[i][j] = {0.f, 0.f, 0.f, 0.f};

#pragma unroll
    for (int k0 = 0; k0 < 128; k0 += 64) {
        __syncthreads();
        {   // merge-staging of A
            int sr = tid >> 1, sc = (tid & 1) * 32;
            int q = m0 + sr;
            int hh = (k0 + sc) >> 5;
            float lsum = 0.f;
#pragma unroll
            for (int s = 0; s < SPLIT; s++)
                lsum += mll[((size_t)s * 4 + hh) * 4096 + q];
            float am[32];
#pragma unroll
            for (int e = 0; e < 32; e++) am[e] = 0.f;
#pragma unroll
            for (int s = 0; s < SPLIT; s++) {
                const _Float16* p = part + (size_t)s * 524288 + (size_t)q * 128 + k0 + sc;
#pragma unroll
                for (int v = 0; v < 4; v++) {
                    f16x8 t = *(const f16x8*)(p + v * 8);
#pragma unroll
                    for (int e = 0; e < 8; e++) am[v * 8 + e] += (float)t[e];
                }
            }
            float inv = 1.f / lsum;
#pragma unroll
            for (int v = 0; v < 4; v++) {
                f16x8 hv;
#pragma unroll
                for (int e = 0; e < 8; e++) hv[e] = (_Float16)(am[v * 8 + e] * inv);
                *(f16x8*)&Ah[sr][sc + v * 8] = hv;
            }
        }
        stageB_f32(Bh, W, 128, 0, k0, tid);
        __syncthreads();
        mfma_tiles(Ah, Bh, wrow, wcol, lc, lr, acc);
    }

#pragma unroll
    for (int i = 0; i < 4; i++) {
        int mb = m0 + wrow + i * 16 + lr * 4;
#pragma unroll
        for (int j = 0; j < 4; j++) {
            int n = wcol + j * 16 + lc;
            float bb = bias[n];
#pragma unroll
            for (int r = 0; r < 4; r++)
                acc[i][j][r] += bb + x[(size_t)(mb + r) * 128 + n];
        }
    }
#pragma unroll
    for (int i = 0; i < 4; i++)
#pragma unroll
        for (int r = 0; r < 4; r++) {
            float s1 = 0.f, s2 = 0.f;
#pragma unroll
            for (int j = 0; j < 4; j++) {
                float t = acc[i][j][r];
                s1 += t; s2 += t * t;
            }
#pragma unroll
            for (int off = 1; off < 16; off <<= 1) {
                s1 += __shfl_xor(s1, off);
                s2 += __shfl_xor(s2, off);
            }
            if (lc == 0) {
                int rl = wrow + i * 16 + lr * 4 + r;
                Red[rl][w & 1][0] = s1;
                Red[rl][w & 1][1] = s2;
            }
        }
    __syncthreads();
#pragma unroll
    for (int i = 0; i < 4; i++)
#pragma unroll
        for (int r = 0; r < 4; r++) {
            int rl = wrow + i * 16 + lr * 4 + r;
            float S1 = Red[rl][0][0] + Red[rl][1][0];
            float S2 = Red[rl][0][1] + Red[rl][1][1];
            float mean = S1 * (1.0f / 128.0f);
            float var = S2 * (1.0f / 128.0f) - mean * mean;
            float inv = rsqrtf(var + 1e-5f);
            int m = m0 + rl;
#pragma unroll
            for (int j = 0; j < 4; j++) {
                int n = wcol + j * 16 + lc;
                float o = (acc[i][j][r] - mean) * inv * g[n] + b[n];
                x[(size_t)m * 128 + n] = o;
                xh[(size_t)m * 128 + n] = (_Float16)o;
            }
        }
}

// ---------------------------------------------------------------------------
// W1 GEMM (relu) -> fh fp16 [4096][1024]. grid (32, 8).  (R9 lesson: keep the
// 256-block grid for weight streaming.)
// ---------------------------------------------------------------------------
__global__ __launch_bounds__(256) void gemm_w1(const _Float16* __restrict__ xh,
                                               const float* __restrict__ W,
                                               const float* __restrict__ bias,
                                               _Float16* __restrict__ fh)
{
    __shared__ _Float16 Ah[128][72], Bh[128][72];
    int tid = threadIdx.x, w = tid >> 6, l = tid & 63, lc = l & 15, lr = l >> 4;
    int wrow = (w >> 1) * 64, wcol = (w & 1) * 64;
    int m0 = blockIdx.x * 128, n0 = blockIdx.y * 128;

    f32x4 acc[4][4];
#pragma unroll
    for (int i = 0; i < 4; i++)
#pragma unroll
        for (int j = 0; j < 4; j++) acc[i][j] = {0.f, 0.f, 0.f, 0.f};

#pragma unroll
    for (int k0 = 0; k0 < 128; k0 += 64) {
        __syncthreads();
        stageA_f16(Ah, xh, 128, m0, k0, tid);
        stageB_f32(Bh, W, 128, n0, k0, tid);
        __syncthreads();
        mfma_tiles(Ah, Bh, wrow, wcol, lc, lr, acc);
    }

#pragma unroll
    for (int i = 0; i < 4; i++) {
        int mb = m0 + wrow + i * 16 + lr * 4;
#pragma unroll
        for (int j = 0; j < 4; j++) {
            int n = n0 + wcol + j * 16 + lc;
            float bb = bias[n];
#pragma unroll
            for (int r = 0; r < 4; r++)
                fh[(size_t)(mb + r) * 1024 + n] =
                    (_Float16)fmaxf(acc[i][j][r] + bb, 0.f);
        }
    }
}

// ---------------------------------------------------------------------------
// W2 GEMM split-K: fp16 partial slabs. grid (32, 1, 8).
// ---------------------------------------------------------------------------
__global__ __launch_bounds__(256) void gemm_w2(const _Float16* __restrict__ fh,
                                               const float* __restrict__ W,
                                               _Float16* __restrict__ wpart)
{
    __shared__ _Float16 Ah[128][72], Bh[128][72];
    int tid = threadIdx.x, w = tid >> 6, l = tid & 63, lc = l & 15, lr = l >> 4;
    int wrow = (w >> 1) * 64, wcol = (w & 1) * 64;
    int m0 = blockIdx.x * 128, kbase = blockIdx.z * 128;

    f32x4 acc[4][4];
#pragma unroll
    for (int i = 0; i < 4; i++)
#pragma unroll
        for (int j = 0; j < 4; j++) acc[i][j] = {0.f, 0.f, 0.f, 0.f};

#pragma unroll
    for (int k0 = 0; k0 < 128; k0 += 64) {
        __syncthreads();
        stageA_f16(Ah, fh, 1024, m0, kbase + k0, tid);
        stageB_f32(Bh, W, 1024, 0, kbase + k0, tid);
        __syncthreads();
        mfma_tiles(Ah, Bh, wrow, wcol, lc, lr, acc);
    }

    _Float16* pz = wpart + (size_t)blockIdx.z * 524288;
#pragma unroll
    for (int i = 0; i < 4; i++) {
        int mb = m0 + wrow + i * 16 + lr * 4;
#pragma unroll
        for (int j = 0; j < 4; j++) {
            int n = wcol + j * 16 + lc;
#pragma unroll
            for (int r = 0; r < 4; r++)
                pz[(size_t)(mb + r) * 128 + n] = (_Float16)acc[i][j][r];
        }
    }
}

// ---------------------------------------------------------------------------
// reduce 8 fp16 W2 partials + bias + residual + LayerNorm -> x, xh.
// ---------------------------------------------------------------------------
__global__ __launch_bounds__(256) void reduce8_ln(const _Float16* __restrict__ part,
                                                  const float* __restrict__ bias,
                                                  float* __restrict__ x,
                                                  _Float16* __restrict__ xh,
                                                  const float* __restrict__ g,
                                                  const float* __restrict__ b)
{
    int row  = blockIdx.x * 4 + (threadIdx.x >> 6);
    int lane = threadIdx.x & 63;
    size_t base = (size_t)row * 128;
    int c = lane * 2;
    float a0 = 0.f, a1 = 0.f;
#pragma unroll
    for (int s = 0; s < 8; s++) {
        f16x2 p = *(const f16x2*)&part[(size_t)s * 524288 + base + c];
        a0 += (float)p[0]; a1 += (float)p[1];
    }
    float2 bv = *(const float2*)&bias[c];
    float2 xv = *(const float2*)&x[base + c];
    a0 += bv.x + xv.x; a1 += bv.y + xv.y;
    float s = a0 + a1;
#pragma unroll
    for (int off = 32; off; off >>= 1) s += __shfl_xor(s, off);
    float mean = s * (1.0f / 128.0f);
    float d0 = a0 - mean, d1 = a1 - mean;
    float v = d0 * d0 + d1 * d1;
#pragma unroll
    for (int off = 32; off; off >>= 1) v += __shfl_xor(v, off);
    float inv = rsqrtf(v * (1.0f / 128.0f) + 1e-5f);
    float2 gv = *(const float2*)&g[c];
    float2 bb = *(const float2*)&b[c];
    float o0 = d0 * inv * gv.x + bb.x, o1 = d1 * inv * gv.y + bb.y;
    float2 r; r.x = o0; r.y = o1;
    *(float2*)&x[base + c] = r;
    f16x2 rh = {(_Float16)o0, (_Float16)o1};
    *(f16x2*)&xh[base + c] = rh;
}

// ---------------------------------------------------------------------------
// fc1 + relu + fc2 + rownorm fused. grid (32). Writes aoh fp16.
// ---------------------------------------------------------------------------
__global__ __launch_bounds__(256) void fc_fused(const _Float16* __restrict__ xh,
                                                const float* __restrict__ W1f,
                                                const float* __restrict__ b1f,
                                                const float* __restrict__ W2f,
                                                const float* __restrict__ b2f,
                                                _Float16* __restrict__ aoh)
{
    __shared__ _Float16 Ah[128][72], Bh[128][72];
    __shared__ _Float16 X2[128][136];
    __shared__ float Red[128][2];
    int tid = threadIdx.x, w = tid >> 6, l = tid & 63, lc = l & 15, lr = l >> 4;
    int wrow = (w >> 1) * 64, wcol = (w & 1) * 64;
    int m0 = blockIdx.x * 128;

    f32x4 acc[4][4];
#pragma unroll
    for (int i = 0; i < 4; i++)
#pragma unroll
        for (int j = 0; j < 4; j++) acc[i][j] = {0.f, 0.f, 0.f, 0.f};

#pragma unroll
    for (int k0 = 0; k0 < 128; k0 += 64) {
        __syncthreads();
        stageA_f16(Ah, xh, 128, m0, k0, tid);
        stageB_f32(Bh, W1f, 128, 0, k0, tid);
        __syncthreads();
        mfma_tiles(Ah, Bh, wrow, wcol, lc, lr, acc);
    }
#pragma unroll
    for (int i = 0; i < 4; i++)
#pragma unroll
        for (int j = 0; j < 4; j++) {
            int n = wcol + j * 16 + lc;
            float bb = b1f[n];
#pragma unroll
            for (int r = 0; r < 4; r++)
                X2[wrow + i * 16 + lr * 4 + r][n] =
                    (_Float16)fmaxf(acc[i][j][r] + bb, 0.f);
        }
#pragma unroll
    for (int i = 0; i < 4; i++)
#pragma unroll
        for (int j = 0; j < 4; j++) acc[i][j] = {0.f, 0.f, 0.f, 0.f};

#pragma unroll
    for (int k0 = 0; k0 < 128; k0 += 64) {
        __syncthreads();
        stageB_f32(Bh, W2f, 128, 0, k0, tid);
        __syncthreads();
#pragma unroll
        for (int ks = 0; ks < 2; ks++) {
            f16x8 afr[4], bfr[4];
#pragma unroll
            for (int t = 0; t < 4; t++) {
                afr[t] = *(const f16x8*)&X2[wrow + t * 16 + lc][k0 + ks * 32 + lr * 8];
                bfr[t] = *(const f16x8*)&Bh[wcol + t * 16 + lc][ks * 32 + lr * 8];
            }
#pragma unroll
            for (int i = 0; i < 4; i++)
#pragma unroll
                for (int j = 0; j < 4; j++)
                    acc[i][j] = __builtin_amdgcn_mfma_f32_16x16x32_f16(
                        afr[i], bfr[j], acc[i][j], 0, 0, 0);
        }
    }

#pragma unroll
    for (int i = 0; i < 4; i++)
#pragma unroll
        for (int j = 0; j < 4; j++) {
            float bb = b2f[wcol + j * 16 + lc];
#pragma unroll
            for (int r = 0; r < 4; r++) acc[i][j][r] += bb;
        }
#pragma unroll
    for (int i = 0; i < 4; i++)
#pragma unroll
        for (int r = 0; r < 4; r++) {
            float s2 = 0.f;
#pragma unroll
            for (int j = 0; j < 4; j++) s2 += acc[i][j][r] * acc[i][j][r];
#pragma unroll
            for (int off = 1; off < 16; off <<= 1) s2 += __shfl_xor(s2, off);
            if (lc == 0) Red[wrow + i * 16 + lr * 4 + r][w & 1] = s2;
        }
    __syncthreads();
#pragma unroll
    for (int i = 0; i < 4; i++)
#pragma unroll
        for (int r = 0; r < 4; r++) {
            int rl = wrow + i * 16 + lr * 4 + r;
            float inv = rsqrtf(Red[rl][0] + Red[rl][1]);
            int m = m0 + rl;
#pragma unroll
            for (int j = 0; j < 4; j++) {
                int n = wcol + j * 16 + lc;
                aoh[(size_t)m * 128 + n] = (_Float16)(acc[i][j][r] * inv);
            }
        }
}

// ---------------------------------------------------------------------------
// Gram: C = max(aoh @ aoh^T, 1e-6), fp32 out. grid (32, 32).
// ---------------------------------------------------------------------------
__global__ __launch_bounds__(256) void gram_f16(const _Float16* __restrict__ aoh,
                                                float* __restrict__ C)
{
    __shared__ _Float16 Ah[128][72], Bh[128][72];
    int tid = threadIdx.x, w = tid >> 6, l = tid & 63, lc = l & 15, lr = l >> 4;
    int wrow = (w >> 1) * 64, wcol = (w & 1) * 64;
    int m0 = blockIdx.x * 128, n0 = blockIdx.y * 128;

    f32x4 acc[4][4];
#pragma unroll
    for (int i = 0; i < 4; i++)
#pragma unroll
        for (int j = 0; j < 4; j++) acc[i][j] = {0.f, 0.f, 0.f, 0.f};

#pragma unroll
    for (int k0 = 0; k0 < 128; k0 += 64) {
        __syncthreads();
        stageA_f16(Ah, aoh, 128, m0, k0, tid);
        stageA_f16(Bh, aoh, 128, n0, k0, tid);
        __syncthreads();
        mfma_tiles(Ah, Bh, wrow, wcol, lc, lr, acc);
    }

#pragma unroll
    for (int i = 0; i < 4; i++) {
        int mb = m0 + wrow + i * 16 + lr * 4;
#pragma unroll
        for (int j = 0; j < 4; j++) {
            int n = n0 + wcol + j * 16 + lc;
#pragma unroll
            for (int r = 0; r < 4; r++)
                C[(size_t)(mb + r) * 4096 + n] = fmaxf(acc[i][j][r], 1e-6f);
        }
    }
}

// ---------------------------------------------------------------------------
extern "C" void kernel_launch(void* const* d_in, const int* in_sizes, int n_in,
                              void* d_out, int out_size, void* d_ws, size_t ws_size,
                              hipStream_t stream)
{
    const float* src  = (const float*)d_in[0];
    const float* Wqkv = (const float*)d_in[1];
    const float* bqkv = (const float*)d_in[2];
    const float* Wo   = (const float*)d_in[3];
    const float* bo   = (const float*)d_in[4];
    const float* ln1g = (const float*)d_in[5];
    const float* ln1b = (const float*)d_in[6];
    const float* W1   = (const float*)d_in[7];
    const float* b1   = (const float*)d_in[8];
    const float* W2   = (const float*)d_in[9];
    const float* b2   = (const float*)d_in[10];
    const float* ln2g = (const float*)d_in[11];
    const float* ln2b = (const float*)d_in[12];
    const float* fc1W = (const float*)d_in[13];
    const float* fc1b = (const float*)d_in[14];
    const float* fc2W = (const float*)d_in[15];
    const float* fc2b = (const float*)d_in[16];

    float* ws = (float*)d_ws;
    float*    x   = ws;                                   // 524288 f32
    _Float16* xh  = (_Float16*)(ws + 524288);             // 524288 f16
    _Float16* aoh = (_Float16*)(ws + 786432);             // 524288 f16
    _Float16* qh  = (_Float16*)(ws + 1048576);            // 524288 f16
    _Float16* kh  = (_Float16*)(ws + 1310720);            // 524288 f16
    _Float16* vt  = (_Float16*)(ws + 1572864);            // 524288 f16
    float*    mll = ws + 1835008;                         // 131072 f32

    // d_out scratch (all dead before gram writes). halves offsets:
    _Float16* fh    = (_Float16*)d_out;                       // [0, 4194304)
    _Float16* wpart = (_Float16*)d_out + 4194304;             // [4194304, 8388608)
    _Float16* apart = (_Float16*)d_out + 12582912;            // 8*524288 f16
    float*    out   = (float*)d_out;

    copy_x<<<512, 256, 0, stream>>>(src, x, xh);
    for (int l = 0; l < 3; l++) {
        gemm_qkv<<<dim3(32, 3), 256, 0, stream>>>(xh, Wqkv + l * 49152,
                                                  bqkv + l * 384, qh, kh, vt);
        attn_mfma<<<dim3(64, 4, SPLIT), 256, 0, stream>>>(qh, kh, vt, apart, mll);
        wo_ln_merge<<<32, 256, 0, stream>>>(apart, mll, Wo + l * 16384, bo + l * 128,
                                            x, xh, ln1g + l * 128, ln1b + l * 128);
        gemm_w1<<<dim3(32, 8), 256, 0, stream>>>(xh, W1 + l * 131072, b1 + l * 1024, fh);
        gemm_w2<<<dim3(32, 1, 8), 256, 0, stream>>>(fh, W2 + l * 131072, wpart);
        reduce8_ln<<<1024, 256, 0, stream>>>(wpart, b2 + l * 128, x, xh,
                                             ln2g + l * 128, ln2b + l * 128);
    }
    fc_fused<<<32, 256, 0, stream>>>(xh, fc1W, fc1b, fc2W, fc2b, aoh);
    gram_f16<<<dim3(32, 32), 256, 0, stream>>>(aoh, out);
}

// Round 11
// 341.417 us; speedup vs baseline: 1.5336x; 1.0466x over previous
//
#include <hip/hip_runtime.h>
#include <math.h>

#define S 4096
#define QK_SCALE 0.17677669529663687f  // 1/sqrt(32)
#define LOG2E    1.44269504088896f
#define SPLIT 8
#define KS (S / SPLIT)                 // 512 keys per split

typedef _Float16 f16x8 __attribute__((ext_vector_type(8)));
typedef _Float16 f16x4 __attribute__((ext_vector_type(4)));
typedef _Float16 f16x2 __attribute__((ext_vector_type(2)));
typedef float f32x4 __attribute__((ext_vector_type(4)));

// ---------------------------------------------------------------------------
// MFMA lane map (HW-verified R4): A-frag m=l&15, k=(l>>4)*8+j; B-frag n=l&15;
// C reg r: row=(l>>4)*4+r, col=l&15. 128x128 block tile, 4 waves (64x64 each).
// R9 lesson: weight-streaming kernels need >=256 blocks; per-block weight
// traffic must stay O(100KB) — per-CU load BW (~10-20 B/cyc) is the wall.
// ---------------------------------------------------------------------------
__device__ __forceinline__ void stageA_f16(_Float16 (*dst)[72], const _Float16* src,
                                           int ld, int row0, int col0, int tid) {
    int sr = tid >> 1, sc = (tid & 1) * 32;
    const _Float16* p = src + (size_t)(row0 + sr) * ld + col0 + sc;
#pragma unroll
    for (int v = 0; v < 4; v++)
        *(f16x8*)&dst[sr][sc + v * 8] = *(const f16x8*)(p + v * 8);
}

__device__ __forceinline__ void stageB_f32(_Float16 (*dst)[72], const float* src,
                                           int ld, int row0, int col0, int tid) {
    int sr = tid >> 1, sc = (tid & 1) * 32;
    const float* p = src + (size_t)(row0 + sr) * ld + col0 + sc;
#pragma unroll
    for (int v = 0; v < 4; v++) {
        float4 a = ((const float4*)p)[v * 2];
        float4 b = ((const float4*)p)[v * 2 + 1];
        f16x8 h = {(_Float16)a.x, (_Float16)a.y, (_Float16)a.z, (_Float16)a.w,
                   (_Float16)b.x, (_Float16)b.y, (_Float16)b.z, (_Float16)b.w};
        *(f16x8*)&dst[sr][sc + v * 8] = h;
    }
}

__device__ __forceinline__ void mfma_tiles(_Float16 (*Ah)[72], _Float16 (*Bh)[72],
                                           int wrow, int wcol, int lc, int lr,
                                           f32x4 acc[4][4]) {
#pragma unroll
    for (int ks = 0; ks < 2; ks++) {
        f16x8 afr[4], bfr[4];
#pragma unroll
        for (int t = 0; t < 4; t++) {
            afr[t] = *(const f16x8*)&Ah[wrow + t * 16 + lc][ks * 32 + lr * 8];
            bfr[t] = *(const f16x8*)&Bh[wcol + t * 16 + lc][ks * 32 + lr * 8];
        }
#pragma unroll
        for (int i = 0; i < 4; i++)
#pragma unroll
            for (int j = 0; j < 4; j++)
                acc[i][j] = __builtin_amdgcn_mfma_f32_16x16x32_f16(
                    afr[i], bfr[j], acc[i][j], 0, 0, 0);
    }
}

// ---------------------------------------------------------------------------
// copy: x(fp32), xh(fp16) <- src
// ---------------------------------------------------------------------------
__global__ __launch_bounds__(256) void copy_x(const float* __restrict__ a,
                                              float* __restrict__ x,
                                              _Float16* __restrict__ xh) {
    int i = blockIdx.x * 256 + threadIdx.x;
    float4 v = ((const float4*)a)[i];
    ((float4*)x)[i] = v;
    f16x4 h = {(_Float16)v.x, (_Float16)v.y, (_Float16)v.z, (_Float16)v.w};
    ((f16x4*)xh)[i] = h;
}

// ---------------------------------------------------------------------------
// QKV GEMM, fused output conversion. grid (32, 3): by=0 -> qh (scaled by
// QK_SCALE*log2e for exp2 softmax), by=1 -> kh, by=2 -> vt (transposed).
// ---------------------------------------------------------------------------
__global__ __launch_bounds__(256) void gemm_qkv(const _Float16* __restrict__ xh,
                                                const float* __restrict__ W,
                                                const float* __restrict__ bias,
                                                _Float16* __restrict__ qh,
                                                _Float16* __restrict__ kh,
                                                _Float16* __restrict__ vt)
{
    __shared__ _Float16 Ah[128][72], Bh[128][72];
    int tid = threadIdx.x, w = tid >> 6, l = tid & 63, lc = l & 15, lr = l >> 4;
    int wrow = (w >> 1) * 64, wcol = (w & 1) * 64;
    int m0 = blockIdx.x * 128, by = blockIdx.y;

    f32x4 acc[4][4];
#pragma unroll
    for (int i = 0; i < 4; i++)
#pragma unroll
        for (int j = 0; j < 4; j++) acc[i][j] = {0.f, 0.f, 0.f, 0.f};

#pragma unroll
    for (int k0 = 0; k0 < 128; k0 += 64) {
        __syncthreads();
        stageA_f16(Ah, xh, 128, m0, k0, tid);
        stageB_f32(Bh, W, 128, by * 128, k0, tid);
        __syncthreads();
        mfma_tiles(Ah, Bh, wrow, wcol, lc, lr, acc);
    }

#pragma unroll
    for (int i = 0; i < 4; i++) {
        int mb = m0 + wrow + i * 16 + lr * 4;
#pragma unroll
        for (int j = 0; j < 4; j++) {
            int n = wcol + j * 16 + lc;
            float bb = bias[by * 128 + n];
            if (by == 0) {
#pragma unroll
                for (int r = 0; r < 4; r++)
                    qh[(size_t)(mb + r) * 128 + n] =
                        (_Float16)((acc[i][j][r] + bb) * (QK_SCALE * LOG2E));
            } else if (by == 1) {
                int hh = n >> 5, d = n & 31;
#pragma unroll
                for (int r = 0; r < 4; r++)
                    kh[((size_t)hh * S + mb + r) * 32 + d] =
                        (_Float16)(acc[i][j][r] + bb);
            } else {
                f16x4 pk;
#pragma unroll
                for (int r = 0; r < 4; r++) pk[r] = (_Float16)(acc[i][j][r] + bb);
                *(f16x4*)&vt[(size_t)n * S + mb] = pk;
            }
        }
    }
}

// ---------------------------------------------------------------------------
// MFMA flash attention, split-K over keys: no online max (scores bounded),
// exp2, per-lane l accumulation, fp16 partials.
// ---------------------------------------------------------------------------
__global__ __launch_bounds__(256) void attn_mfma(const _Float16* __restrict__ qh,
                                                 const _Float16* __restrict__ kh,
                                                 const _Float16* __restrict__ vt,
                                                 _Float16* __restrict__ part,
                                                 float* __restrict__ mll)
{
    __shared__ _Float16 Ks[64][48];
    __shared__ _Float16 Vt[32][72];
    __shared__ _Float16 Ps[4][16][72];
    int h = blockIdx.y, q0 = blockIdx.x * 64, z = blockIdx.z;
    int tid = threadIdx.x;
    int w = tid >> 6, l = tid & 63;
    int lc = l & 15, lr = l >> 4;

    f16x8 qf = *(const f16x8*)&qh[(size_t)(q0 + w * 16 + lc) * 128 + h * 32 + lr * 8];

    f32x4 o0 = {0.f, 0.f, 0.f, 0.f}, o1 = {0.f, 0.f, 0.f, 0.f};
    float lp[4] = {0.f, 0.f, 0.f, 0.f};

    const _Float16* khh = kh + (size_t)h * S * 32;
    const _Float16* vth = vt + (size_t)h * 32 * S;

    for (int k0 = z * KS; k0 < z * KS + KS; k0 += 64) {
        __syncthreads();
        {
            int row = tid >> 2, dg = (tid & 3) * 8;
            *(f16x8*)&Ks[row][dg] = *(const f16x8*)&khh[(size_t)(k0 + row) * 32 + dg];
            int dim = tid >> 3, kg = (tid & 7) * 8;
            *(f16x8*)&Vt[dim][kg] = *(const f16x8*)&vth[(size_t)dim * S + k0 + kg];
        }
        __syncthreads();

        f32x4 st[4];
#pragma unroll
        for (int t = 0; t < 4; t++) {
            f16x8 kf = *(const f16x8*)&Ks[t * 16 + lc][lr * 8];
            f32x4 zz = {0.f, 0.f, 0.f, 0.f};
            st[t] = __builtin_amdgcn_mfma_f32_16x16x32_f16(qf, kf, zz, 0, 0, 0);
        }

#pragma unroll
        for (int i = 0; i < 4; i++) {
            float p0 = exp2f(st[0][i]), p1 = exp2f(st[1][i]);
            float p2 = exp2f(st[2][i]), p3 = exp2f(st[3][i]);
            lp[i] += (p0 + p1) + (p2 + p3);
            Ps[w][lr * 4 + i][lc]      = (_Float16)p0;
            Ps[w][lr * 4 + i][16 + lc] = (_Float16)p1;
            Ps[w][lr * 4 + i][32 + lc] = (_Float16)p2;
            Ps[w][lr * 4 + i][48 + lc] = (_Float16)p3;
        }
        asm volatile("s_waitcnt lgkmcnt(0)" ::: "memory");
#pragma unroll
        for (int ch = 0; ch < 2; ch++) {
            f16x8 pf = *(const f16x8*)&Ps[w][lc][ch * 32 + lr * 8];
            f16x8 v0 = *(const f16x8*)&Vt[lc][ch * 32 + lr * 8];
            f16x8 v1 = *(const f16x8*)&Vt[16 + lc][ch * 32 + lr * 8];
            o0 = __builtin_amdgcn_mfma_f32_16x16x32_f16(pf, v0, o0, 0, 0, 0);
            o1 = __builtin_amdgcn_mfma_f32_16x16x32_f16(pf, v1, o1, 0, 0, 0);
        }
    }

#pragma unroll
    for (int i = 0; i < 4; i++) {
#pragma unroll
        for (int off = 1; off < 16; off <<= 1) lp[i] += __shfl_xor(lp[i], off);
    }

    _Float16* pz = part + (size_t)z * 524288;
#pragma unroll
    for (int i = 0; i < 4; i++) {
        int q = q0 + w * 16 + lr * 4 + i;
        pz[(size_t)q * 128 + h * 32 + lc]      = (_Float16)o0[i];
        pz[(size_t)q * 128 + h * 32 + 16 + lc] = (_Float16)o1[i];
        if (lc == 0) mll[((size_t)z * 4 + h) * 4096 + q] = lp[i];
    }
}

// ---------------------------------------------------------------------------
// Wo GEMM with the split-attention MERGE fused into A-staging, + residual +
// LayerNorm epilogue. grid (32).
// ---------------------------------------------------------------------------
__global__ __launch_bounds__(256) void wo_ln_merge(const _Float16* __restrict__ part,
                                                   const float* __restrict__ mll,
                                                   const float* __restrict__ W,
                                                   const float* __restrict__ bias,
                                                   float* __restrict__ x,
                                                   _Float16* __restrict__ xh,
                                                   const float* __restrict__ g,
                                                   const float* __restrict__ b)
{
    __shared__ _Float16 Ah[128][72], Bh[128][72];
    __shared__ float Red[128][2][2];
    int tid = threadIdx.x, w = tid >> 6, l = tid & 63, lc = l & 15, lr = l >> 4;
    int wrow = (w >> 1) * 64, wcol = (w & 1) * 64;
    int m0 = blockIdx.x * 128;

    f32x4 acc[4][4];
#pragma unroll
    for (int i = 0; i < 4; i++)
#pragma unroll
        for (int j = 0; j < 4; j++) acc[i][j] = {0.f, 0.f, 0.f, 0.f};

#pragma unroll
    for (int k0 = 0; k0 < 128; k0 += 64) {
        __syncthreads();
        {   // merge-staging of A
            int sr = tid >> 1, sc = (tid & 1) * 32;
            int q = m0 + sr;
            int hh = (k0 + sc) >> 5;
            float lsum = 0.f;
#pragma unroll
            for (int s = 0; s < SPLIT; s++)
                lsum += mll[((size_t)s * 4 + hh) * 4096 + q];
            float am[32];
#pragma unroll
            for (int e = 0; e < 32; e++) am[e] = 0.f;
#pragma unroll
            for (int s = 0; s < SPLIT; s++) {
                const _Float16* p = part + (size_t)s * 524288 + (size_t)q * 128 + k0 + sc;
#pragma unroll
                for (int v = 0; v < 4; v++) {
                    f16x8 t = *(const f16x8*)(p + v * 8);
#pragma unroll
                    for (int e = 0; e < 8; e++) am[v * 8 + e] += (float)t[e];
                }
            }
            float inv = 1.f / lsum;
#pragma unroll
            for (int v = 0; v < 4; v++) {
                f16x8 hv;
#pragma unroll
                for (int e = 0; e < 8; e++) hv[e] = (_Float16)(am[v * 8 + e] * inv);
                *(f16x8*)&Ah[sr][sc + v * 8] = hv;
            }
        }
        stageB_f32(Bh, W, 128, 0, k0, tid);
        __syncthreads();
        mfma_tiles(Ah, Bh, wrow, wcol, lc, lr, acc);
    }

#pragma unroll
    for (int i = 0; i < 4; i++) {
        int mb = m0 + wrow + i * 16 + lr * 4;
#pragma unroll
        for (int j = 0; j < 4; j++) {
            int n = wcol + j * 16 + lc;
            float bb = bias[n];
#pragma unroll
            for (int r = 0; r < 4; r++)
                acc[i][j][r] += bb + x[(size_t)(mb + r) * 128 + n];
        }
    }
#pragma unroll
    for (int i = 0; i < 4; i++)
#pragma unroll
        for (int r = 0; r < 4; r++) {
            float s1 = 0.f, s2 = 0.f;
#pragma unroll
            for (int j = 0; j < 4; j++) {
                float t = acc[i][j][r];
                s1 += t; s2 += t * t;
            }
#pragma unroll
            for (int off = 1; off < 16; off <<= 1) {
                s1 += __shfl_xor(s1, off);
                s2 += __shfl_xor(s2, off);
            }
            if (lc == 0) {
                int rl = wrow + i * 16 + lr * 4 + r;
                Red[rl][w & 1][0] = s1;
                Red[rl][w & 1][1] = s2;
            }
        }
    __syncthreads();
#pragma unroll
    for (int i = 0; i < 4; i++)
#pragma unroll
        for (int r = 0; r < 4; r++) {
            int rl = wrow + i * 16 + lr * 4 + r;
            float S1 = Red[rl][0][0] + Red[rl][1][0];
            float S2 = Red[rl][0][1] + Red[rl][1][1];
            float mean = S1 * (1.0f / 128.0f);
            float var = S2 * (1.0f / 128.0f) - mean * mean;
            float inv = rsqrtf(var + 1e-5f);
            int m = m0 + rl;
#pragma unroll
            for (int j = 0; j < 4; j++) {
                int n = wcol + j * 16 + lc;
                float o = (acc[i][j][r] - mean) * inv * g[n] + b[n];
                x[(size_t)m * 128 + n] = o;
                xh[(size_t)m * 128 + n] = (_Float16)o;
            }
        }
}

// ---------------------------------------------------------------------------
// Fused W1+W2 pair, grid (32 m-tiles, 8 K-chunks) = 256 blocks (R9 lesson:
// keep weight streaming parallel; 128 KB weights per block). Block (m,c):
//   Fh = relu(x_m @ W1_c^T + b1_c)   (128x128, LDS-only)
//   wpart[c] = Fh @ W2[:, c*128:+128]^T   (fp16 split-K slab)
// ---------------------------------------------------------------------------
__global__ __launch_bounds__(256) void ffn_pair(const _Float16* __restrict__ xh,
                                                const float* __restrict__ W1,
                                                const float* __restrict__ b1,
                                                const float* __restrict__ W2,
                                                _Float16* __restrict__ wpart)
{
    __shared__ _Float16 Ah[128][72], Bh[128][72];
    __shared__ _Float16 Fh[128][140];
    int tid = threadIdx.x, w = tid >> 6, l = tid & 63, lc = l & 15, lr = l >> 4;
    int wrow = (w >> 1) * 64, wcol = (w & 1) * 64;
    int m0 = blockIdx.x * 128, c = blockIdx.y;

    // pass 1: fh chunk
    f32x4 facc[4][4];
#pragma unroll
    for (int i = 0; i < 4; i++)
#pragma unroll
        for (int j = 0; j < 4; j++) facc[i][j] = {0.f, 0.f, 0.f, 0.f};
#pragma unroll
    for (int k0 = 0; k0 < 128; k0 += 64) {
        __syncthreads();
        stageA_f16(Ah, xh, 128, m0, k0, tid);
        stageB_f32(Bh, W1, 128, c * 128, k0, tid);
        __syncthreads();
        mfma_tiles(Ah, Bh, wrow, wcol, lc, lr, facc);
    }
    // relu + bias -> Fh (C-layout scatter into A-layout LDS; wave w writes
    // rows wrow..+63, cols wcol..+63 — pass 2 reads cross-wave, barrier below)
#pragma unroll
    for (int i = 0; i < 4; i++)
#pragma unroll
        for (int j = 0; j < 4; j++) {
            int n = wcol + j * 16 + lc;
            float bb = b1[c * 128 + n];
#pragma unroll
            for (int r = 0; r < 4; r++)
                Fh[wrow + i * 16 + lr * 4 + r][n] =
                    (_Float16)fmaxf(facc[i][j][r] + bb, 0.f);
        }

    // pass 2: partial = Fh @ W2-chunk^T
    f32x4 oacc[4][4];
#pragma unroll
    for (int i = 0; i < 4; i++)
#pragma unroll
        for (int j = 0; j < 4; j++) oacc[i][j] = {0.f, 0.f, 0.f, 0.f};
#pragma unroll
    for (int k0 = 0; k0 < 128; k0 += 64) {
        __syncthreads();   // Fh ready (k0=0) / prev Bh reads done
        stageB_f32(Bh, W2, 1024, 0, c * 128 + k0, tid);
        __syncthreads();
#pragma unroll
        for (int ks = 0; ks < 2; ks++) {
            f16x8 afr[4], bfr[4];
#pragma unroll
            for (int t = 0; t < 4; t++) {
                afr[t] = *(const f16x8*)&Fh[wrow + t * 16 + lc][k0 + ks * 32 + lr * 8];
                bfr[t] = *(const f16x8*)&Bh[wcol + t * 16 + lc][ks * 32 + lr * 8];
            }
#pragma unroll
            for (int i = 0; i < 4; i++)
#pragma unroll
                for (int j = 0; j < 4; j++)
                    oacc[i][j] = __builtin_amdgcn_mfma_f32_16x16x32_f16(
                        afr[i], bfr[j], oacc[i][j], 0, 0, 0);
        }
    }

    _Float16* pz = wpart + (size_t)c * 524288;
#pragma unroll
    for (int i = 0; i < 4; i++) {
        int mb = m0 + wrow + i * 16 + lr * 4;
#pragma unroll
        for (int j = 0; j < 4; j++) {
            int n = wcol + j * 16 + lc;
#pragma unroll
            for (int r = 0; r < 4; r++)
                pz[(size_t)(mb + r) * 128 + n] = (_Float16)oacc[i][j][r];
        }
    }
}

// ---------------------------------------------------------------------------
// reduce 8 fp16 W2 partials + bias + residual + LayerNorm -> x, xh.
// ---------------------------------------------------------------------------
__global__ __launch_bounds__(256) void reduce8_ln(const _Float16* __restrict__ part,
                                                  const float* __restrict__ bias,
                                                  float* __restrict__ x,
                                                  _Float16* __restrict__ xh,
                                                  const float* __restrict__ g,
                                                  const float* __restrict__ b)
{
    int row  = blockIdx.x * 4 + (threadIdx.x >> 6);
    int lane = threadIdx.x & 63;
    size_t base = (size_t)row * 128;
    int c = lane * 2;
    float a0 = 0.f, a1 = 0.f;
#pragma unroll
    for (int s = 0; s < 8; s++) {
        f16x2 p = *(const f16x2*)&part[(size_t)s * 524288 + base + c];
        a0 += (float)p[0]; a1 += (float)p[1];
    }
    float2 bv = *(const float2*)&bias[c];
    float2 xv = *(const float2*)&x[base + c];
    a0 += bv.x + xv.x; a1 += bv.y + xv.y;
    float s = a0 + a1;
#pragma unroll
    for (int off = 32; off; off >>= 1) s += __shfl_xor(s, off);
    float mean = s * (1.0f / 128.0f);
    float d0 = a0 - mean, d1 = a1 - mean;
    float v = d0 * d0 + d1 * d1;
#pragma unroll
    for (int off = 32; off; off >>= 1) v += __shfl_xor(v, off);
    float inv = rsqrtf(v * (1.0f / 128.0f) + 1e-5f);
    float2 gv = *(const float2*)&g[c];
    float2 bb = *(const float2*)&b[c];
    float o0 = d0 * inv * gv.x + bb.x, o1 = d1 * inv * gv.y + bb.y;
    float2 r; r.x = o0; r.y = o1;
    *(float2*)&x[base + c] = r;
    f16x2 rh = {(_Float16)o0, (_Float16)o1};
    *(f16x2*)&xh[base + c] = rh;
}

// ---------------------------------------------------------------------------
// fc1 + relu + fc2 + rownorm fused. grid (32). Writes aoh fp16.
// ---------------------------------------------------------------------------
__global__ __launch_bounds__(256) void fc_fused(const _Float16* __restrict__ xh,
                                                const float* __restrict__ W1f,
                                                const float* __restrict__ b1f,
                                                const float* __restrict__ W2f,
                                                const float* __restrict__ b2f,
                                                _Float16* __restrict__ aoh)
{
    __shared__ _Float16 Ah[128][72], Bh[128][72];
    __shared__ _Float16 X2[128][136];
    __shared__ float Red[128][2];
    int tid = threadIdx.x, w = tid >> 6, l = tid & 63, lc = l & 15, lr = l >> 4;
    int wrow = (w >> 1) * 64, wcol = (w & 1) * 64;
    int m0 = blockIdx.x * 128;

    f32x4 acc[4][4];
#pragma unroll
    for (int i = 0; i < 4; i++)
#pragma unroll
        for (int j = 0; j < 4; j++) acc[i][j] = {0.f, 0.f, 0.f, 0.f};

#pragma unroll
    for (int k0 = 0; k0 < 128; k0 += 64) {
        __syncthreads();
        stageA_f16(Ah, xh, 128, m0, k0, tid);
        stageB_f32(Bh, W1f, 128, 0, k0, tid);
        __syncthreads();
        mfma_tiles(Ah, Bh, wrow, wcol, lc, lr, acc);
    }
#pragma unroll
    for (int i = 0; i < 4; i++)
#pragma unroll
        for (int j = 0; j < 4; j++) {
            int n = wcol + j * 16 + lc;
            float bb = b1f[n];
#pragma unroll
            for (int r = 0; r < 4; r++)
                X2[wrow + i * 16 + lr * 4 + r][n] =
                    (_Float16)fmaxf(acc[i][j][r] + bb, 0.f);
        }
#pragma unroll
    for (int i = 0; i < 4; i++)
#pragma unroll
        for (int j = 0; j < 4; j++) acc[i][j] = {0.f, 0.f, 0.f, 0.f};

#pragma unroll
    for (int k0 = 0; k0 < 128; k0 += 64) {
        __syncthreads();
        stageB_f32(Bh, W2f, 128, 0, k0, tid);
        __syncthreads();
#pragma unroll
        for (int ks = 0; ks < 2; ks++) {
            f16x8 afr[4], bfr[4];
#pragma unroll
            for (int t = 0; t < 4; t++) {
                afr[t] = *(const f16x8*)&X2[wrow + t * 16 + lc][k0 + ks * 32 + lr * 8];
                bfr[t] = *(const f16x8*)&Bh[wcol + t * 16 + lc][ks * 32 + lr * 8];
            }
#pragma unroll
            for (int i = 0; i < 4; i++)
#pragma unroll
                for (int j = 0; j < 4; j++)
                    acc[i][j] = __builtin_amdgcn_mfma_f32_16x16x32_f16(
                        afr[i], bfr[j], acc[i][j], 0, 0, 0);
        }
    }

#pragma unroll
    for (int i = 0; i < 4; i++)
#pragma unroll
        for (int j = 0; j < 4; j++) {
            float bb = b2f[wcol + j * 16 + lc];
#pragma unroll
            for (int r = 0; r < 4; r++) acc[i][j][r] += bb;
        }
#pragma unroll
    for (int i = 0; i < 4; i++)
#pragma unroll
        for (int r = 0; r < 4; r++) {
            float s2 = 0.f;
#pragma unroll
            for (int j = 0; j < 4; j++) s2 += acc[i][j][r] * acc[i][j][r];
#pragma unroll
            for (int off = 1; off < 16; off <<= 1) s2 += __shfl_xor(s2, off);
            if (lc == 0) Red[wrow + i * 16 + lr * 4 + r][w & 1] = s2;
        }
    __syncthreads();
#pragma unroll
    for (int i = 0; i < 4; i++)
#pragma unroll
        for (int r = 0; r < 4; r++) {
            int rl = wrow + i * 16 + lr * 4 + r;
            float inv = rsqrtf(Red[rl][0] + Red[rl][1]);
            int m = m0 + rl;
#pragma unroll
            for (int j = 0; j < 4; j++) {
                int n = wcol + j * 16 + lc;
                aoh[(size_t)m * 128 + n] = (_Float16)(acc[i][j][r] * inv);
            }
        }
}

// ---------------------------------------------------------------------------
// Gram: C = max(aoh @ aoh^T, 1e-6), fp32 out. grid (32, 32).
// ---------------------------------------------------------------------------
__global__ __launch_bounds__(256) void gram_f16(const _Float16* __restrict__ aoh,
                                                float* __restrict__ C)
{
    __shared__ _Float16 Ah[128][72], Bh[128][72];
    int tid = threadIdx.x, w = tid >> 6, l = tid & 63, lc = l & 15, lr = l >> 4;
    int wrow = (w >> 1) * 64, wcol = (w & 1) * 64;
    int m0 = blockIdx.x * 128, n0 = blockIdx.y * 128;

    f32x4 acc[4][4];
#pragma unroll
    for (int i = 0; i < 4; i++)
#pragma unroll
        for (int j = 0; j < 4; j++) acc[i][j] = {0.f, 0.f, 0.f, 0.f};

#pragma unroll
    for (int k0 = 0; k0 < 128; k0 += 64) {
        __syncthreads();
        stageA_f16(Ah, aoh, 128, m0, k0, tid);
        stageA_f16(Bh, aoh, 128, n0, k0, tid);
        __syncthreads();
        mfma_tiles(Ah, Bh, wrow, wcol, lc, lr, acc);
    }

#pragma unroll
    for (int i = 0; i < 4; i++) {
        int mb = m0 + wrow + i * 16 + lr * 4;
#pragma unroll
        for (int j = 0; j < 4; j++) {
            int n = n0 + wcol + j * 16 + lc;
#pragma unroll
            for (int r = 0; r < 4; r++)
                C[(size_t)(mb + r) * 4096 + n] = fmaxf(acc[i][j][r], 1e-6f);
        }
    }
}

// ---------------------------------------------------------------------------
extern "C" void kernel_launch(void* const* d_in, const int* in_sizes, int n_in,
                              void* d_out, int out_size, void* d_ws, size_t ws_size,
                              hipStream_t stream)
{
    const float* src  = (const float*)d_in[0];
    const float* Wqkv = (const float*)d_in[1];
    const float* bqkv = (const float*)d_in[2];
    const float* Wo   = (const float*)d_in[3];
    const float* bo   = (const float*)d_in[4];
    const float* ln1g = (const float*)d_in[5];
    const float* ln1b = (const float*)d_in[6];
    const float* W1   = (const float*)d_in[7];
    const float* b1   = (const float*)d_in[8];
    const float* W2   = (const float*)d_in[9];
    const float* b2   = (const float*)d_in[10];
    const float* ln2g = (const float*)d_in[11];
    const float* ln2b = (const float*)d_in[12];
    const float* fc1W = (const float*)d_in[13];
    const float* fc1b = (const float*)d_in[14];
    const float* fc2W = (const float*)d_in[15];
    const float* fc2b = (const float*)d_in[16];

    float* ws = (float*)d_ws;
    float*    x   = ws;                                   // 524288 f32
    _Float16* xh  = (_Float16*)(ws + 524288);             // 524288 f16
    _Float16* aoh = (_Float16*)(ws + 786432);             // 524288 f16
    _Float16* qh  = (_Float16*)(ws + 1048576);            // 524288 f16
    _Float16* kh  = (_Float16*)(ws + 1310720);            // 524288 f16
    _Float16* vt  = (_Float16*)(ws + 1572864);            // 524288 f16
    float*    mll = ws + 1835008;                         // 131072 f32

    // d_out scratch (all dead before gram writes):
    _Float16* wpart = (_Float16*)d_out + 4194304;             // 8*524288 f16
    _Float16* apart = (_Float16*)d_out + 12582912;            // 8*524288 f16
    float*    out   = (float*)d_out;

    copy_x<<<512, 256, 0, stream>>>(src, x, xh);
    for (int l = 0; l < 3; l++) {
        gemm_qkv<<<dim3(32, 3), 256, 0, stream>>>(xh, Wqkv + l * 49152,
                                                  bqkv + l * 384, qh, kh, vt);
        attn_mfma<<<dim3(64, 4, SPLIT), 256, 0, stream>>>(qh, kh, vt, apart, mll);
        wo_ln_merge<<<32, 256, 0, stream>>>(apart, mll, Wo + l * 16384, bo + l * 128,
                                            x, xh, ln1g + l * 128, ln1b + l * 128);
        ffn_pair<<<dim3(32, 8), 256, 0, stream>>>(xh, W1 + l * 131072, b1 + l * 1024,
                                                  W2 + l * 131072, wpart);
        reduce8_ln<<<1024, 256, 0, stream>>>(wpart, b2 + l * 128, x, xh,
                                             ln2g + l * 128, ln2b + l * 128);
    }
    fc_fused<<<32, 256, 0, stream>>>(xh, fc1W, fc1b, fc2W, fc2b, aoh);
    gram_f16<<<dim3(32, 32), 256, 0, stream>>>(aoh, out);
}